// Round 7
// baseline (2019.297 us; speedup 1.0000x reference)
//
#include <hip/hip_runtime.h>

typedef unsigned short u16;
typedef _Float16 f16x8_t __attribute__((ext_vector_type(8)));
typedef short    i16x8_t __attribute__((ext_vector_type(8)));
typedef float    f32x4_t __attribute__((ext_vector_type(4)));

#define SCOPE_AGENT __HIP_MEMORY_SCOPE_AGENT

// ---- helpers ---------------------------------------------------------------
static __device__ __forceinline__ u16 f2h(float f) {
  _Float16 h = (_Float16)f;  // RNE
  return __builtin_bit_cast(u16, h);
}
static __device__ __forceinline__ f32x4_t mfma16h(i16x8_t a, i16x8_t b, f32x4_t c) {
  return __builtin_amdgcn_mfma_f32_16x16x32_f16(
      __builtin_bit_cast(f16x8_t, a), __builtin_bit_cast(f16x8_t, b), c, 0, 0, 0);
}
static __device__ __forceinline__ float sigmoidf_(float x) { return 1.f / (1.f + __expf(-x)); }
static __device__ __forceinline__ float tanhf_(float x) { return 1.f - 2.f / (__expf(2.f * x) + 1.f); }

// ---- prep: LSTM weights pre-swizzled per (dir,q) block, MFMA frag order ----
// layout linear = ((((dir*4+q)*16 + nt)*12 + kb)*64 + lane)*8 + e
// nt = g*4 + sub; n = g*256 + q*64 + sub*16 + mrow; k = kb*32 + quad*8 + e
__global__ __launch_bounds__(256) void prep_wpack(const float* __restrict__ Wi_f,
                                                  const float* __restrict__ Wh_f,
                                                  const float* __restrict__ Wi_r,
                                                  const float* __restrict__ Wh_r,
                                                  u16* __restrict__ wpack) {
  int id = blockIdx.x * 256 + threadIdx.x;
  if (id >= 786432) return;  // 2*4*16*12*64*8
  int tmp = id;
  int e = tmp & 7; tmp >>= 3;
  int lane = tmp & 63; tmp >>= 6;
  int kb = tmp % 12; tmp /= 12;
  int nt = tmp & 15; tmp >>= 4;
  int q = tmp & 3;
  int dir = tmp >> 2;
  int mrow = lane & 15, quad = lane >> 4;
  int g = nt >> 2, sub = nt & 3;
  int n = g * 256 + q * 64 + sub * 16 + mrow;
  int k = kb * 32 + quad * 8 + e;
  const float* Wi = dir ? Wi_r : Wi_f;
  const float* Wh = dir ? Wh_r : Wh_f;
  float v = (k < 128) ? Wi[k * 1024 + n] : Wh[(k - 128) * 1024 + n];
  wpack[id] = f2h(v);
}

// ---- prep: MLP W^T in f16 (W1[512][256], W2[256][256], W3[256][128]) -------
__global__ __launch_bounds__(256) void prep_small(const float* __restrict__ W1,
                                                  const float* __restrict__ W2,
                                                  const float* __restrict__ W3,
                                                  u16* __restrict__ w1t,
                                                  u16* __restrict__ w2t,
                                                  u16* __restrict__ w3t) {
  int id = blockIdx.x * 256 + threadIdx.x;
  if (id < 131072) { int n = id >> 9, k = id & 511; w1t[id] = f2h(W1[k * 256 + n]); return; }
  id -= 131072;
  if (id < 65536) { int n = id >> 8, k = id & 255; w2t[id] = f2h(W2[k * 256 + n]); return; }
  id -= 65536;
  if (id < 32768) { int n = id >> 8, k = id & 255; w3t[id] = f2h(W3[k * 128 + n]); }
}

// ---- bidirectional LSTM v4: weight-stationary cluster design ---------------
// 256 blocks = dir(2) x bg(32) x q(4); block owns 16 batch rows x 64 j-cols
// (x all 4 gates), weights ALL in VGPRs. Cluster = 4 blocks with same
// (dir,bg); per-step h exchange through x1 (t-versioned, always-cold lines)
// with release/acquire flags. All 256 blocks co-resident (1 block/CU).
__global__ __launch_bounds__(512, 2) void lstm_kernel(
    const float* __restrict__ x0, const u16* __restrict__ wpack,
    const float* __restrict__ bi_f, const float* __restrict__ bh_f,
    const float* __restrict__ bi_r, const float* __restrict__ bh_r,
    u16* __restrict__ x1, int* __restrict__ flags) {
  __shared__ __align__(16) u16 panel[16][392];    // [m][k]: 0:128 x_t, 128:384 h
  __shared__ float aobuf[2][16][68];              // gates a,o exchange (fp32)

  const int tid = threadIdx.x;
  const int lane = tid & 63;
  const int w = tid >> 6;              // 8 waves
  const int sub = w & 3;               // j-sub-tile (16 cols)
  const int gh = w >> 2;               // 0: gates f,i   1: gates a,o
  const int bx = blockIdx.x;
  const int dir = bx >> 7, rr = bx & 127, bg = rr >> 2, q = rr & 3;
  const int b0 = bg * 16;
  const int mrow = lane & 15, quad = lane >> 4;

  // flags: one int per block; publish-then-wait protocol
  const int myf = bx;
  int peer[3];
  { int c_ = 0;
    for (int q2 = 0; q2 < 4; ++q2) if (q2 != q) peer[c_++] = (bx & ~3) | q2; }
  if (tid == 0)
    __hip_atomic_store(&flags[myf], 0, __ATOMIC_RELAXED, SCOPE_AGENT);

  const float* bi = dir ? bi_r : bi_f;
  const float* bh = dir ? bh_r : bh_f;
  const int nt0 = (gh * 2 + 0) * 4 + sub;
  const int nt1 = (gh * 2 + 1) * 4 + sub;
  const int ncol = q * 64 + sub * 16 + mrow;
  const float bias0 = bi[(gh * 2 + 0) * 256 + ncol] + bh[(gh * 2 + 0) * 256 + ncol];
  const float bias1 = bi[(gh * 2 + 1) * 256 + ncol] + bh[(gh * 2 + 1) * 256 + ncol];

  // register-resident weights: 2 tiles x 12 kb x 16 B/lane = 96 VGPRs
  const u16* wb = wpack + (size_t)((dir * 4 + q) * 16) * 12 * 512;
  i16x8_t w0[12], w1[12];
#pragma unroll
  for (int kb = 0; kb < 12; ++kb) {
    w0[kb] = *(const i16x8_t*)(wb + (size_t)(nt0 * 12 + kb) * 512 + lane * 8);
    w1[kb] = *(const i16x8_t*)(wb + (size_t)(nt1 * 12 + kb) * 512 + lane * 8);
  }

  float c_[4] = {0.f, 0.f, 0.f, 0.f};

#pragma unroll 1
  for (int t = 0; t < 128; ++t) {
    __syncthreads();  // B1: drains prev step's x1 stores + all ds ops
    if (tid == 0 && t > 0) {
      // publish h_{t-1} (release flushes this XCD's L2 to coherence point)
      __hip_atomic_store(&flags[myf], t, __ATOMIC_RELEASE, SCOPE_AGENT);
#pragma unroll 1
      for (int p = 0; p < 3; ++p)
        while (__hip_atomic_load(&flags[peer[p]], __ATOMIC_ACQUIRE, SCOPE_AGENT) < t)
          __builtin_amdgcn_s_sleep(1);
    }
    __syncthreads();  // B2: release whole block after spin

    // stage x_t (16 rows x 128 cols, float4/thread)
    {
      int row = tid >> 5, c4 = (tid & 31) * 4;
      int teff = dir ? (127 - t) : t;
      float4 v = *(const float4*)(x0 + (((b0 + row) * 128 + teff) << 7) + c4);
      ushort4 hv = {f2h(v.x), f2h(v.y), f2h(v.z), f2h(v.w)};
      *(ushort4*)&panel[row][c4] = hv;
    }
    // stage peer h slices from x1[t-1] (addresses cold: t-versioned)
    if (t > 0) {
      int row = tid >> 5, c2 = (tid & 31) * 2;
      const u16* src = x1 + ((size_t)((b0 + row) * 128 + (t - 1))) * 512 + dir * 256;
#pragma unroll
      for (int p = 0; p < 3; ++p) {
        int jg = ((peer[p] & 3) << 6) + c2;
        *(unsigned*)&panel[row][128 + jg] = *(const unsigned*)(src + jg);
      }
    } else {
      int row = tid >> 5, cb = (tid & 31) * 8;
#pragma unroll
      for (int i = 0; i < 8; ++i) panel[row][128 + cb + i] = 0;
    }
    __syncthreads();  // B3: panel ready

    // A-fragments + MFMA (2 n-tiles per wave, K=384)
    i16x8_t af[12];
#pragma unroll
    for (int kb = 0; kb < 12; ++kb)
      af[kb] = *(const i16x8_t*)&panel[mrow][kb * 32 + quad * 8];
    f32x4_t a0 = {bias0, bias0, bias0, bias0};
    f32x4_t a1 = {bias1, bias1, bias1, bias1};
#pragma unroll
    for (int kb = 0; kb < 12; ++kb) a0 = mfma16h(af[kb], w0[kb], a0);
#pragma unroll
    for (int kb = 0; kb < 12; ++kb) a1 = mfma16h(af[kb], w1[kb], a1);

    if (gh == 1) {  // write gates a,o for the update waves
      int jl = sub * 16 + mrow;
#pragma unroll
      for (int r = 0; r < 4; ++r) {
        aobuf[0][quad * 4 + r][jl] = a0[r];
        aobuf[1][quad * 4 + r][jl] = a1[r];
      }
    }
    __syncthreads();  // B4: aobuf ready

    if (gh == 0) {  // gate update: lane owns (m = quad*4+r, j = q*64+jl)
      int jl = sub * 16 + mrow;
      int jg = (q << 6) + jl;
#pragma unroll
      for (int r = 0; r < 4; ++r) {
        int m = quad * 4 + r;
        float ag = aobuf[0][m][jl];
        float og = aobuf[1][m][jl];
        float cv = sigmoidf_(a0[r]) * c_[r] + sigmoidf_(a1[r]) * tanhf_(ag);
        c_[r] = cv;
        float hv = sigmoidf_(og) * tanhf_(cv);
        u16 hb = f2h(hv);
        panel[m][128 + jg] = hb;  // own slice for next step (local)
        x1[((size_t)((b0 + m) * 128 + t)) * 512 + dir * 256 + jg] = hb;
      }
    }
  }
}

// ---- fused MLP + heads (unchanged — passing) -------------------------------
__global__ __launch_bounds__(512, 1) void mlp_kernel(
    const u16* __restrict__ x1, const u16* __restrict__ w1t,
    const u16* __restrict__ w2t, const u16* __restrict__ w3t,
    const float* __restrict__ b1, const float* __restrict__ b2,
    const float* __restrict__ b3, float* __restrict__ out) {
  __shared__ __align__(16) u16 X2[128][264];
  __shared__ __align__(16) u16 X3[128][264];
  const int tid = threadIdx.x;
  const int lane = tid & 63, wv = tid >> 6;
  const int mrow = lane & 15, quad = lane >> 4;
  const int r0 = blockIdx.x * 128;
  const f32x4_t zero4 = {0.f, 0.f, 0.f, 0.f};

  // stage 1: X2[128][256] = leaky(x1[128,512] @ W1 + b1)
  {
    f32x4_t acc[16];
#pragma unroll
    for (int n = 0; n < 16; ++n) acc[n] = zero4;
    for (int kb = 0; kb < 16; ++kb) {
      int k = kb * 32 + quad * 8;
      i16x8_t a = *(const i16x8_t*)(x1 + (size_t)(r0 + wv * 16 + mrow) * 512 + k);
#pragma unroll
      for (int n = 0; n < 16; ++n) {
        i16x8_t b = *(const i16x8_t*)(w1t + (n * 16 + mrow) * 512 + k);
        acc[n] = mfma16h(a, b, acc[n]);
      }
    }
#pragma unroll
    for (int n = 0; n < 16; ++n)
#pragma unroll
      for (int r = 0; r < 4; ++r) {
        int m = wv * 16 + quad * 4 + r;
        int col = n * 16 + mrow;
        float v = acc[n][r] + b1[col];
        v = v > 0.f ? v : 0.1f * v;
        X2[m][col] = f2h(v);
      }
  }
  __syncthreads();

  // stage 2: X3[128][256] = leaky(X2 @ W2 + b2), K=256
  {
    f32x4_t acc[16];
#pragma unroll
    for (int n = 0; n < 16; ++n) acc[n] = zero4;
#pragma unroll
    for (int kb = 0; kb < 8; ++kb) {
      int k = kb * 32 + quad * 8;
      i16x8_t a = *(const i16x8_t*)&X2[wv * 16 + mrow][k];
#pragma unroll
      for (int n = 0; n < 16; ++n) {
        i16x8_t b = *(const i16x8_t*)(w2t + (n * 16 + mrow) * 256 + k);
        acc[n] = mfma16h(a, b, acc[n]);
      }
    }
#pragma unroll
    for (int n = 0; n < 16; ++n)
#pragma unroll
      for (int r = 0; r < 4; ++r) {
        int m = wv * 16 + quad * 4 + r;
        int col = n * 16 + mrow;
        float v = acc[n][r] + b2[col];
        v = v > 0.f ? v : 0.1f * v;
        X3[m][col] = f2h(v);
      }
  }
  __syncthreads();

  // stage 3: XF[128][128] = X3 @ W3 + b3 (fp32; overlays dead X2)
  float (*XF)[130] = (float (*)[130]) & X2[0][0];
  {
    f32x4_t acc[8];
#pragma unroll
    for (int n = 0; n < 8; ++n) acc[n] = zero4;
#pragma unroll
    for (int kb = 0; kb < 8; ++kb) {
      int k = kb * 32 + quad * 8;
      i16x8_t a = *(const i16x8_t*)&X3[wv * 16 + mrow][k];
#pragma unroll
      for (int n = 0; n < 8; ++n) {
        i16x8_t b = *(const i16x8_t*)(w3t + (n * 16 + mrow) * 256 + k);
        acc[n] = mfma16h(a, b, acc[n]);
      }
    }
#pragma unroll
    for (int n = 0; n < 8; ++n)
#pragma unroll
      for (int r = 0; r < 4; ++r) {
        int m = wv * 16 + quad * 4 + r;
        int col = n * 16 + mrow;
        XF[m][col] = acc[n][r] + b3[col];
      }
  }
  __syncthreads();

  // heads: cols 0:64 sigmoid; softmax over [64,72), [72,88), [88,128)
  if (tid < 128) {
    int row = tid;
    float* xr = XF[row];
    float* op = out + (size_t)(r0 + row) * 128;
    for (int cc = 0; cc < 64; ++cc) op[cc] = sigmoidf_(xr[cc]);
  } else if (tid < 256) {
    int row = tid - 128;
    float* xr = XF[row];
    float* op = out + (size_t)(r0 + row) * 128;
    const int s0s[3] = {64, 72, 88};
    const int s1s[3] = {72, 88, 128};
    for (int s = 0; s < 3; ++s) {
      int s0 = s0s[s], s1 = s1s[s];
      float mx = xr[s0];
      for (int qq = s0 + 1; qq < s1; ++qq) mx = fmaxf(mx, xr[qq]);
      float sum = 0.f;
      for (int qq = s0; qq < s1; ++qq) { float e = __expf(xr[qq] - mx); xr[qq] = e; sum += e; }
      float inv = 1.f / sum;
      for (int qq = s0; qq < s1; ++qq) op[qq] = xr[qq] * inv;
    }
  }
}

// ---- launch ----------------------------------------------------------------
extern "C" void kernel_launch(void* const* d_in, const int* in_sizes, int n_in,
                              void* d_out, int out_size, void* d_ws, size_t ws_size,
                              hipStream_t stream) {
  const float* x0   = (const float*)d_in[0];
  const float* Wi_f = (const float*)d_in[1];
  const float* bi_f = (const float*)d_in[2];
  const float* Wh_f = (const float*)d_in[3];
  const float* bh_f = (const float*)d_in[4];
  const float* Wi_r = (const float*)d_in[5];
  const float* bi_r = (const float*)d_in[6];
  const float* Wh_r = (const float*)d_in[7];
  const float* bh_r = (const float*)d_in[8];
  const float* W1 = (const float*)d_in[9];
  const float* b1 = (const float*)d_in[10];
  const float* W2 = (const float*)d_in[11];
  const float* b2 = (const float*)d_in[12];
  const float* W3 = (const float*)d_in[13];
  const float* b3 = (const float*)d_in[14];
  float* out = (float*)d_out;

  char* ws = (char*)d_ws;
  u16* w1t   = (u16*)(ws + 0);         // 262144 B
  u16* w2t   = (u16*)(ws + 262144);    // 131072 B
  u16* w3t   = (u16*)(ws + 393216);    // 65536 B
  u16* wpack = (u16*)(ws + 458752);    // 1572864 B
  int* flags = (int*)(ws + 2031616);   // 1024 B
  u16* x1    = (u16*)(ws + 2032640);   // 67108864 B

  hipLaunchKernelGGL(prep_wpack, dim3(3072), dim3(256), 0, stream,
                     Wi_f, Wh_f, Wi_r, Wh_r, wpack);
  hipLaunchKernelGGL(prep_small, dim3(896), dim3(256), 0, stream,
                     W1, W2, W3, w1t, w2t, w3t);
  hipLaunchKernelGGL(lstm_kernel, dim3(256), dim3(512), 0, stream,
                     x0, wpack, bi_f, bh_f, bi_r, bh_r, x1, flags);
  hipLaunchKernelGGL(mlp_kernel, dim3(512), dim3(512), 0, stream,
                     x1, w1t, w2t, w3t, b1, b2, b3, out);
}